// Round 11
// baseline (51.556 us; speedup 1.0000x reference)
//
#include <hip/hip_runtime.h>

#define WL 512   // window_len (t and o dims)
#define NV 64    // n_var
#define LR 16    // low rank
#define NB 512   // batch
#define BB 8     // batches per k_out block
#define OO 8     // o-rows per k_out block

__device__ __forceinline__ float tanh_fast(float x) {
    // tanh(x) = 1 - 2/(exp(2x)+1); exact at +-inf saturation, ~1e-7 abs err
    float e = __expf(2.0f * x);
    return 1.0f - 2.0f / (e + 1.0f);
}

// K1: tmp[b,k,v] = sum_t tanh(g[v]*x[b,t,v]) * A[t,k]
// grid = 512 (one block per b), block = 1024 threads (16 waves).
// (byte-identical to R7's verified 47.85us version)
__global__ __launch_bounds__(1024, 8) void k_tmp(
    const float* __restrict__ x, const float* __restrict__ gating,
    const float* __restrict__ A, float* __restrict__ tmp)
{
    __shared__ float red[16 * LR * NV];  // 64 KiB (16 partials x 1024 (k,v))
    const int tid = threadIdx.x;
    const int b = blockIdx.x;

    const int v = tid & 63;
    const int tg = __builtin_amdgcn_readfirstlane(tid >> 6);
    const float g = gating[v];

    float acc[LR];
#pragma unroll
    for (int k = 0; k < LR; ++k) acc[k] = 0.f;

    const float* xb = x + (size_t)b * (WL * NV) + (size_t)tg * 32 * NV + v;
    const float* Abase = A + (size_t)tg * 32 * LR;

#pragma unroll 4
    for (int i = 0; i < 32; ++i) {
        const float x1 = tanh_fast(g * xb[i * NV]);      // 256B/wave, coalesced
        const float* Ar = Abase + i * LR;                // wave-uniform -> s_load
#pragma unroll
        for (int k = 0; k < LR; ++k) acc[k] = fmaf(x1, Ar[k], acc[k]);
    }

#pragma unroll
    for (int k = 0; k < LR; ++k) red[(tg * LR + k) * NV + v] = acc[k];
    __syncthreads();

    {
        const int p = tid;
        float s = 0.f;
#pragma unroll
        for (int t = 0; t < 16; ++t) s += red[t * (LR * NV) + p];
        tmp[(size_t)b * (LR * NV) + p] = s;
    }
}

// K2: out[b,o,v] = x[b,o,v] + bias[o,v] + sum_k tmp[b,k,v]*B[k,o,v]
// grid = (64 b-chunks of 8) x (64 o-tiles of 8), block = 256 (4 waves)
//
// ALLOCATOR-INDEPENDENT REDESIGN: R6/R8/R9/R10 showed the register allocator
// never grants B-panel residency (VGPR_Count always ~half the cap; pins ->
// scratch spill) so B was refetched from L2 every batch (~1.07 GB ~= 30us at
// the 34.5 TB/s L2 ceiling = K2's measured wall). Fix: stage BOTH reused
// operands in LDS. B_lds 32 KB + T_lds 32 KB = 64 KB -> 2 blocks/CU.
// Every B/tmp element enters the block exactly once (B traffic 8x lower);
// inner-loop reads are conflict-free ds_read_b32 (lanes = consecutive v),
// bounded at ~5-7us/CU even with ZERO register caching — the failure mode
// that ate rounds 6-10 is structurally impossible here.
// thread: v = tid&63, wave wv = tid>>6 owns o_local = wv*2 + {0,1}.
__global__ __attribute__((amdgpu_flat_work_group_size(256, 256),
                          amdgpu_waves_per_eu(2, 2)))
void k_out(
    const float* __restrict__ x, const float* __restrict__ bias,
    const float* __restrict__ Bm, const float* __restrict__ tmp,
    float* __restrict__ out)
{
    __shared__ float B_lds[OO * LR * NV];  // [o][k][v] 32 KiB
    __shared__ float T_lds[BB * LR * NV];  // [b][k][v] 32 KiB (linear tmp slice)
    const int tid = threadIdx.x;
    const int v = tid & 63;
    const int wv = tid >> 6;               // 0..3
    const int o0 = blockIdx.y * OO;
    const int b0 = blockIdx.x * BB;

    // stage B slice: 8192 floats = 2048 float4, coalesced
#pragma unroll
    for (int i = 0; i < 8; ++i) {
        const int fidx = i * 256 + tid;    // float4 index 0..2047
        const int ko = fidx >> 4;          // 0..127 = (o_local, k)
        const int v4 = fidx & 15;
        const int ol = ko >> 4;            // 0..7
        const int k  = ko & 15;
        const float4 val = *(const float4*)(Bm + ((size_t)k * WL + (o0 + ol)) * NV + v4 * 4);
        *(float4*)(B_lds + ((ol * LR + k) * NV) + v4 * 4) = val;
    }
    // stage tmp slice: fully linear 8192 floats
    {
        const float4* src = (const float4*)(tmp + (size_t)b0 * (LR * NV));
        float4* dst = (float4*)T_lds;
#pragma unroll
        for (int i = 0; i < 8; ++i) dst[i * 256 + tid] = src[i * 256 + tid];
    }
    __syncthreads();

    const int ol0 = wv * 2;
    float Breg[2][LR];                     // small; cacheable even at tight budgets
#pragma unroll
    for (int j = 0; j < 2; ++j)
#pragma unroll
        for (int k = 0; k < LR; ++k)
            Breg[j][k] = B_lds[((ol0 + j) * LR + k) * NV + v];  // conflict-free
    float breg[2];
#pragma unroll
    for (int j = 0; j < 2; ++j) breg[j] = bias[(o0 + ol0 + j) * NV + v];

    // x prefetched one batch ahead (only long-latency chain left)
    float xr[2], xrn[2];
    {
        const float* xb = x + (size_t)b0 * (WL * NV);
#pragma unroll
        for (int j = 0; j < 2; ++j) xr[j] = xb[(o0 + ol0 + j) * NV + v];
    }

    for (int bl = 0; bl < BB; ++bl) {
        const int b = b0 + bl;
        if (bl + 1 < BB) {
            const float* xb = x + (size_t)(b + 1) * (WL * NV);
#pragma unroll
            for (int j = 0; j < 2; ++j) xrn[j] = xb[(o0 + ol0 + j) * NV + v];
        }

        float tr[LR];
#pragma unroll
        for (int k = 0; k < LR; ++k) tr[k] = T_lds[(bl * LR + k) * NV + v];  // conflict-free

        float* ob = out + (size_t)b * (WL * NV);
#pragma unroll
        for (int j = 0; j < 2; ++j) {
            float acc = breg[j];
#pragma unroll
            for (int k = 0; k < LR; ++k) acc += tr[k] * Breg[j][k];
            ob[(o0 + ol0 + j) * NV + v] = xr[j] + acc;
        }

        if (bl + 1 < BB) { xr[0] = xrn[0]; xr[1] = xrn[1]; }
    }
}

extern "C" void kernel_launch(void* const* d_in, const int* in_sizes, int n_in,
                              void* d_out, int out_size, void* d_ws, size_t ws_size,
                              hipStream_t stream) {
    const float* x      = (const float*)d_in[0];  // [512,512,64,1]
    const float* gating = (const float*)d_in[1];  // [64]
    const float* bias   = (const float*)d_in[2];  // [512,64]
    const float* A      = (const float*)d_in[3];  // [512,16]
    const float* Bm     = (const float*)d_in[4];  // [16,512,64]
    float* out = (float*)d_out;
    float* tmp = (float*)d_ws;                    // 2 MiB scratch ([b,k,v])

    k_tmp<<<NB, 1024, 0, stream>>>(x, gating, A, tmp);
    k_out<<<dim3(64, 64), 256, 0, stream>>>(x, bias, Bm, tmp, out);
}